// Round 3
// baseline (264.772 us; speedup 1.0000x reference)
//
#include <hip/hip_runtime.h>

// FromRGB fused pipeline:
//   x[8,16,512,512] --(IHT up2 + blur down2 + Haar down2 composed into one
//   separable 4x4 stride-2 stencil)--> new_in[8,16,256,256]
//   new_in --(1x1 conv 16->512, scale 0.25, +bias, leakyrelu(0.2)*sqrt2)--> out[8,512,256,256]
//
// Composed 1D filters (x16), indexed [analysis][synthesis]:
//   (l,l): [1, 7, 7, 1]   (l,h): [1, 1,-1,-1]
//   (h,l): [1, 5,-5,-1]   (h,h): [1,-1,-1, 1]
// new_in[4*comp+ch](oy,ox) = (1/256) * sum_g s_g *
//     [y-filter(comp,gY) (x) x-filter(comp,gX)] . x[4g+ch][2oy-1..2oy+2][2ox-1..2ox+2]
// comp: 0=ll 1=lh 2=hl 3=hh ; g: 0=ll(+) 1=lh(-) 2=hl(-) 3=hh(+)

#define H_IN 512
#define W_IN 512
#define H_OUT 256
#define W_OUT 256
#define NB 8
#define C_MID 16
#define C_OUT 512

typedef float fx4 __attribute__((ext_vector_type(4)));

__device__ __forceinline__ float cL(int fsel, float a0, float a1, float a2, float a3) {
  // analysis = l; fsel 0 -> [1,7,7,1], 1 -> [1,1,-1,-1]
  return fsel == 0 ? (a0 + 7.f*a1 + 7.f*a2 + a3) : (a0 + a1 - a2 - a3);
}
__device__ __forceinline__ float cH(int fsel, float a0, float a1, float a2, float a3) {
  // analysis = h; fsel 0 -> [1,5,-5,-1], 1 -> [1,-1,-1,1]
  return fsel == 0 ? (a0 + 5.f*a1 - 5.f*a2 - a3) : (a0 - a1 - a2 + a3);
}

// Stage 1: x -> new_in. One thread computes 4 comps x 1 row x 4 cols (16
// outputs) for one (b, ch). 16 row-reads of 10 floats (1 scalar + 2 float4 +
// 1 scalar). Grid 2048 blocks -> 6-8 waves/SIMD for latency hiding.
__global__ __launch_bounds__(256) void k_stage1(const float* __restrict__ x,
                                                float* __restrict__ nin) {
  const int t  = threadIdx.x;
  const int q  = t & 63;                       // output cols 4q..4q+3
  const int oy = blockIdx.x * 4 + (t >> 6);    // one output row (wave-uniform)
  const int bz = blockIdx.y;                   // b*4 + ch
  const int b = bz >> 2, ch = bz & 3;
  const int y0 = 2 * oy - 1;

  const float WL[2][4] = {{1.f, 7.f, 7.f, 1.f}, {1.f, 1.f, -1.f, -1.f}};
  const float WH[2][4] = {{1.f, 5.f, -5.f, -1.f}, {1.f, -1.f, -1.f, 1.f}};

  float acc[4][4];                             // [comp][xo]
#pragma unroll
  for (int i = 0; i < 4; ++i)
#pragma unroll
    for (int k = 0; k < 4; ++k) acc[i][k] = 0.f;

#pragma unroll
  for (int g = 0; g < 4; ++g) {
    const int gY = g & 1, gX = g >> 1;
    const float sg = (g == 1 || g == 2) ? -1.f : 1.f;
    const float* xp = x + (size_t)(b * 16 + g * 4 + ch) * (H_IN * W_IN);
#pragma unroll
    for (int p = 0; p < 4; ++p) {
      const int yy = y0 + p;
      if (yy < 0 || yy >= H_IN) continue;      // wave-uniform branch
      const float* row = xp + (size_t)yy * W_IN + 8 * q;
      float c[10];                             // cols 8q-1 .. 8q+8
      c[0] = (q > 0) ? row[-1] : 0.f;
      const fx4 m0 = *reinterpret_cast<const fx4*>(row);
      const fx4 m1 = *reinterpret_cast<const fx4*>(row + 4);
      c[1] = m0.x; c[2] = m0.y; c[3] = m0.z; c[4] = m0.w;
      c[5] = m1.x; c[6] = m1.y; c[7] = m1.z; c[8] = m1.w;
      c[9] = (q < 63) ? row[8] : 0.f;
      const float wl = sg * WL[gY][p];
      const float wh = sg * WH[gY][p];
#pragma unroll
      for (int xo = 0; xo < 4; ++xo) {
        const float a0 = c[2*xo], a1 = c[2*xo+1], a2 = c[2*xo+2], a3 = c[2*xo+3];
        const float vL = cL(gX, a0, a1, a2, a3);
        const float vH = cH(gX, a0, a1, a2, a3);
        acc[0][xo] = fmaf(wl, vL, acc[0][xo]);
        acc[1][xo] = fmaf(wh, vL, acc[1][xo]);
        acc[2][xo] = fmaf(wl, vH, acc[2][xo]);
        acc[3][xo] = fmaf(wh, vH, acc[3][xo]);
      }
    }
  }

  const float inv = 1.f / 256.f;
#pragma unroll
  for (int comp = 0; comp < 4; ++comp) {
    fx4 r;
    r.x = acc[comp][0] * inv; r.y = acc[comp][1] * inv;
    r.z = acc[comp][2] * inv; r.w = acc[comp][3] * inv;
    *reinterpret_cast<fx4*>(
        nin + ((size_t)(b * 16 + comp * 4 + ch) * H_OUT + oy) * W_OUT + 4 * q) = r;
  }
}

__device__ __forceinline__ fx4 vfma(fx4 v, float s, fx4 a) {
  a.x = fmaf(v.x, s, a.x); a.y = fmaf(v.y, s, a.y);
  a.z = fmaf(v.z, s, a.z); a.w = fmaf(v.w, s, a.w);
  return a;
}

// Stage 2: 1x1 conv 16->512 + bias + leakyrelu*sqrt2, channel-chunked 4-way
// for occupancy. Weights (pre-scaled 0.25) in LDS as float4 (broadcast
// ds_read_b128). Each thread owns 4 x positions of one row and streams 128
// non-temporal float4 stores. UNCHANGED from round 2 for attribution.
__global__ __launch_bounds__(256) void k_stage2(const float* __restrict__ nin,
                                                const float* __restrict__ w,
                                                const float* __restrict__ bias,
                                                float* __restrict__ out) {
  __shared__ fx4 ws4[128 * 4];
  __shared__ float bs[128];
  const int t = threadIdx.x;
  const int chunk = blockIdx.z;                // 0..3 -> channels 128*chunk..+127
  const int obase = 128 * chunk;

  const fx4* w4 = reinterpret_cast<const fx4*>(w + (size_t)obase * 16);
  ws4[t]       = w4[t] * 0.25f;
  ws4[t + 256] = w4[t + 256] * 0.25f;
  if (t < 128) bs[t] = bias[obase + t];
  __syncthreads();

  const int by = blockIdx.x;                   // 0..63
  const int b  = blockIdx.y;                   // 0..7
  const int y  = 4 * by + (t >> 6);
  const int xq = (t & 63) * 4;

  const float* np = nin + ((size_t)(b * C_MID) * H_OUT + y) * W_OUT + xq;
  fx4 v[16];
#pragma unroll
  for (int c = 0; c < 16; ++c)
    v[c] = *reinterpret_cast<const fx4*>(np + (size_t)c * (H_OUT * W_OUT));

  float* op = out + ((size_t)(b * C_OUT + obase) * H_OUT + y) * W_OUT + xq;
  const float s2 = 1.41421356237309515f;
#pragma unroll 2
  for (int o = 0; o < 128; ++o) {
    const fx4 w0 = ws4[4*o], w1 = ws4[4*o+1], w2 = ws4[4*o+2], w3 = ws4[4*o+3];
    const float bo = bs[o];
    fx4 a; a.x = bo; a.y = bo; a.z = bo; a.w = bo;
    a = vfma(v[0],  w0.x, a); a = vfma(v[1],  w0.y, a);
    a = vfma(v[2],  w0.z, a); a = vfma(v[3],  w0.w, a);
    a = vfma(v[4],  w1.x, a); a = vfma(v[5],  w1.y, a);
    a = vfma(v[6],  w1.z, a); a = vfma(v[7],  w1.w, a);
    a = vfma(v[8],  w2.x, a); a = vfma(v[9],  w2.y, a);
    a = vfma(v[10], w2.z, a); a = vfma(v[11], w2.w, a);
    a = vfma(v[12], w3.x, a); a = vfma(v[13], w3.y, a);
    a = vfma(v[14], w3.z, a); a = vfma(v[15], w3.w, a);
    a.x = (a.x >= 0.f ? a.x : 0.2f * a.x) * s2;
    a.y = (a.y >= 0.f ? a.y : 0.2f * a.y) * s2;
    a.z = (a.z >= 0.f ? a.z : 0.2f * a.z) * s2;
    a.w = (a.w >= 0.f ? a.w : 0.2f * a.w) * s2;
    __builtin_nontemporal_store(a,
        reinterpret_cast<fx4*>(op + (size_t)o * (H_OUT * W_OUT)));
  }
}

extern "C" void kernel_launch(void* const* d_in, const int* in_sizes, int n_in,
                              void* d_out, int out_size, void* d_ws, size_t ws_size,
                              hipStream_t stream) {
  const float* x    = (const float*)d_in[0];
  const float* w    = (const float*)d_in[1];
  const float* bias = (const float*)d_in[2];
  float* nin = (float*)d_out;                                       // output 0
  float* out = (float*)d_out + (size_t)NB * C_MID * H_OUT * W_OUT;  // output 1

  k_stage1<<<dim3(64, 32), dim3(256), 0, stream>>>(x, nin);
  k_stage2<<<dim3(64, 8, 4), dim3(256), 0, stream>>>(nin, w, bias, out);
}